// Round 11
// baseline (252.100 us; speedup 1.0000x reference)
//
#include <hip/hip_runtime.h>
#include <math.h>

// Problem constants
#define QN 4096
#define MN 65536
#define DN 384
#define CN 128
#define NCHUNK 64                 // m-chunks
#define MROWS_PER_CHUNK (MN / NCHUNK)   // 1024
#define MT_PER (MROWS_PER_CHUNK / 64)   // 16 m-tiles (64 rows) per block
#define FRAG_B 2048                     // one fragment-major block: 64 lanes x 32B
#define GSTRIDE (3 * FRAG_B)            // bytes per 16-row group (3 kc)
#define TSTRIDE (4 * GSTRIDE)           // bytes per 64-row tile = 24576

typedef __attribute__((ext_vector_type(8))) int i32x8;
typedef __attribute__((ext_vector_type(4))) int i32x4;
typedef __attribute__((ext_vector_type(4))) float f32x4;

__device__ __forceinline__ void async16(const void* g, void* l) {
  __builtin_amdgcn_global_load_lds(
      (const __attribute__((address_space(1))) unsigned int*)g,
      (__attribute__((address_space(3))) unsigned int*)l, 16, 0, 0);
}

// ------- Kernel A: L2-normalize rows (q then m) -> fp8 --------------------
// q-rows: linear layout (consumed by the GEMM's LDS A-stage).
// m-rows: FRAGMENT-MAJOR layout — the exact per-lane register image of the
// MFMA B-operand: addr(g,kc,l) = ((g*3+kc)*64 + l)*32, l = quad*16 + row15,
// lane's 32B = row (l&15), K-bytes [kc*128 + (l>>4)*32, +32). This makes the
// GEMM's B loads global->VGPR perfectly coalesced (lane i at base + i*32),
// eliminating LDS staging entirely (R2 failed only on coalescing; R1 proved
// B is L2-resident).
// Element k=lane*2+i*128 of row mr: kc=i, quad=lane>>4, off=(lane&15)*2;
// consecutive rows write consecutive 32B blocks -> stores coalesce in L2.
__global__ __launch_bounds__(256) void nrm_kernel(const float* __restrict__ qe,
                                                  const float* __restrict__ me,
                                                  unsigned char* __restrict__ yq,
                                                  unsigned char* __restrict__ ym) {
  const int row = blockIdx.x * 4 + (threadIdx.x >> 6);
  const int lane = threadIdx.x & 63;
  const float* xr = (row < QN) ? qe + (size_t)row * DN
                               : me + (size_t)(row - QN) * DN;
  float2 v[3];
  float ss = 0.f;
#pragma unroll
  for (int i = 0; i < 3; ++i) {
    v[i] = *(const float2*)&xr[lane * 2 + i * 128];
    ss += v[i].x * v[i].x + v[i].y * v[i].y;
  }
#pragma unroll
  for (int m = 1; m < 64; m <<= 1) ss += __shfl_xor(ss, m);
  const float scale = 1.0f / fmaxf(sqrtf(ss), 1e-8f);
  if (row < QN) {
    unsigned short* yw = (unsigned short*)(yq + (size_t)row * DN);
#pragma unroll
    for (int i = 0; i < 3; ++i) {
      const int p = __builtin_amdgcn_cvt_pk_fp8_f32(v[i].x * scale,
                                                    v[i].y * scale, 0, false);
      yw[lane + i * 64] = (unsigned short)(p & 0xffff);
    }
  } else {
    const int mr = row - QN;
    const int g = mr >> 4, r15 = mr & 15;
    const int fl = ((lane >> 4) << 4) + r15;   // fragment lane index
    unsigned short* yw = (unsigned short*)ym;
#pragma unroll
    for (int i = 0; i < 3; ++i) {
      const int p = __builtin_amdgcn_cvt_pk_fp8_f32(v[i].x * scale,
                                                    v[i].y * scale, 0, false);
      yw[((size_t)(g * 3 + i) * 64 + fl) * 16 + (lane & 15)] =
          (unsigned short)(p & 0xffff);
    }
  }
}

// ------- Kernel B: MX-fp8 GEMM, barrier-free register-direct B -------------
// R11: B fragments load global->VGPR (coalesced, fragment-major mn8) from
// L2. Main loop: 12 global_load_dwordx4-pairs + 24 MFMA, ZERO barriers, ZERO
// LDS. R3-R10 proved the barriered LDS schedule pins MfmaUtil at ~50% (read
// phase + MFMA phase strictly serialized, phase-alignment is an attractor);
// with no barriers, 8 free-running waves/CU hide L2 latency via TLP (m114).
// Bandwidth: 48KB/CU-visit ~= 860 cyc at per-CU L2 share ~ MFMA 830 cyc,
// wr-twin waves re-read the same fragments so L1 halves L2 traffic.
// A (128x384) staged via LDS once (prologue barriers only), hoisted to regs.
__global__ __launch_bounds__(256, 2) void gemm_max_kernel(
    const unsigned char* __restrict__ qn8, const unsigned char* __restrict__ mn8,
    float* __restrict__ pmax) {
  __shared__ unsigned char As[128 * DN];   // 48 KB: A staging only
  __shared__ float smax[2][128];

  const int tid = threadIdx.x;
  const int wave = tid >> 6, lane = tid & 63;
  const int wr = wave >> 1, wc = wave & 1;   // waves: 2x2 over 128q x 64m
  const int quad = lane >> 4, l16 = lane & 15;
  const int r7 = l16 & 7;

  // --- XCD-partitioned bijective swizzle (HW assigns XCD = linear id % 8) ---
  const int bid = blockIdx.y * gridDim.x + blockIdx.x;  // linear dispatch id
  const int xcd = bid & 7;
  const int j = bid >> 3;                    // 0..255 within this XCD
  const int ychunk = (xcd << 3) | (j >> 5);  // 8 m-chunks per XCD
  const int qrow0 = (j & 31) * 128;          // x sweeps fastest
  const int mchunk0 = ychunk * MROWS_PER_CHUNK;

  float rmax[16];
#pragma unroll
  for (int i = 0; i < 16; ++i) rmax[i] = -3.0e38f;

  // ---- stage A tile (128x384 = 48 KB) once, hoist fragments to registers --
  {
    const unsigned char* abase = qn8 + (size_t)qrow0 * DN;
#pragma unroll
    for (int i = 0; i < 12; ++i) {
      const int ci = i * 256 + tid;               // 16B chunk 0..3071
      const int row = ci / 24;
      const int jj = ci - row * 24;
      const int gj = (jj & 24) | ((jj ^ row) & 7);  // XOR-swizzled source chunk
      async16(abase + row * DN + gj * 16, &As[(i * 256 + wave * 64) * 16]);
    }
  }
  __syncthreads();  // full drain: A staged
  i32x8 afr[3][4];
#pragma unroll
  for (int kc = 0; kc < 3; ++kc)
#pragma unroll
    for (int rt = 0; rt < 4; ++rt) {
      const unsigned char* p = &As[(wr * 64 + rt * 16 + l16) * DN];
      i32x4 lo = *(const i32x4*)&p[(kc * 8 + ((quad * 2 + 0) ^ r7)) * 16];
      i32x4 hi = *(const i32x4*)&p[(kc * 8 + ((quad * 2 + 1) ^ r7)) * 16];
      afr[kc][rt][0] = lo[0]; afr[kc][rt][1] = lo[1];
      afr[kc][rt][2] = lo[2]; afr[kc][rt][3] = lo[3];
      afr[kc][rt][4] = hi[0]; afr[kc][rt][5] = hi[1];
      afr[kc][rt][6] = hi[2]; afr[kc][rt][7] = hi[3];
    }
  // no further LDS use until epilogue; NO barriers in the main loop

  // --- per-wave fragment-major B pointers: ct=0 -> group g0, ct=1 -> g0+1 --
  const int g0 = (mchunk0 >> 4) + wc * 2;
  const unsigned char* bp0 = mn8 + ((size_t)g0 * 3 * 64 + lane) * 32;
  const unsigned char* bp1 = bp0 + GSTRIDE;   // group g0+1

#pragma unroll 1
  for (int mt = 0; mt < MT_PER; ++mt) {
    i32x8 bfr[3][2];
#pragma unroll
    for (int kc = 0; kc < 3; ++kc) {
      bfr[kc][0] = *(const i32x8*)(bp0 + kc * FRAG_B);
      bfr[kc][1] = *(const i32x8*)(bp1 + kc * FRAG_B);
    }

    f32x4 acc[4][2];
#pragma unroll
    for (int rt = 0; rt < 4; ++rt)
#pragma unroll
      for (int ct = 0; ct < 2; ++ct) acc[rt][ct] = (f32x4){0.f, 0.f, 0.f, 0.f};

    __builtin_amdgcn_s_setprio(1);
#pragma unroll
    for (int kc = 0; kc < 3; ++kc)
#pragma unroll
      for (int rt = 0; rt < 4; ++rt)
#pragma unroll
        for (int ct = 0; ct < 2; ++ct)
          acc[rt][ct] = __builtin_amdgcn_mfma_scale_f32_16x16x128_f8f6f4(
              afr[kc][rt], bfr[kc][ct], acc[rt][ct], 0, 0,  // fmt fp8/fp8
              0, 0x7f7f7f7f, 0, 0x7f7f7f7f);                // scales = 1.0
    __builtin_amdgcn_s_setprio(0);

#pragma unroll
    for (int rt = 0; rt < 4; ++rt)
#pragma unroll
      for (int r = 0; r < 4; ++r) {
        const float v = fmaxf(acc[rt][0][r], acc[rt][1][r]);
        rmax[rt * 4 + r] = fmaxf(rmax[rt * 4 + r], v);
      }

    bp0 += TSTRIDE;
    bp1 += TSTRIDE;
  }

#pragma unroll
  for (int i = 0; i < 16; ++i) {
    float v = rmax[i];
    v = fmaxf(v, __shfl_xor(v, 1));
    v = fmaxf(v, __shfl_xor(v, 2));
    v = fmaxf(v, __shfl_xor(v, 4));
    v = fmaxf(v, __shfl_xor(v, 8));
    rmax[i] = v;
  }
  if (l16 == 0) {
#pragma unroll
    for (int rt = 0; rt < 4; ++rt)
#pragma unroll
      for (int r = 0; r < 4; ++r)
        smax[wc][wr * 64 + rt * 16 + quad * 4 + r] = rmax[rt * 4 + r];
  }
  __syncthreads();
  if (tid < 128) {
    const float v = fmaxf(smax[0][tid], smax[1][tid]);
    pmax[(size_t)(qrow0 + tid) * NCHUNK + ychunk] = v;
  }
}

// ------- Kernel C: reduce partials; uniform row OR exact fp32 re-check -----
__global__ __launch_bounds__(256) void decide_kernel(
    const float* __restrict__ pmax, const float* __restrict__ qe,
    const float* __restrict__ me, const float* __restrict__ labels,
    float* __restrict__ out) {
  const int q = blockIdx.x;
  const int t = threadIdx.x;  // 256
  __shared__ float smx;
  if (t < 64) {
    float v = pmax[(size_t)q * NCHUNK + t];  // NCHUNK == 64
#pragma unroll
    for (int m = 1; m < 64; m <<= 1) v = fmaxf(v, __shfl_xor(v, m));
    if (t == 0) smx = v;
  }
  __syncthreads();
  if (smx <= 0.5f) {  // uniform fast path (expected for all queries)
    if (t < CN) out[(size_t)q * CN + t] = 1.0f / 128.0f;
    return;
  }
  // exact fp32 path (rare / borderline queries only)
  __shared__ float sred[256];
  __shared__ int sidx[256];
  __shared__ float wsum[4];
  const float* qr = qe + (size_t)q * DN;
  float ss = 0.f;
  for (int i = t; i < DN; i += 256) ss += qr[i] * qr[i];
#pragma unroll
  for (int m = 1; m < 64; m <<= 1) ss += __shfl_xor(ss, m);
  if ((t & 63) == 0) wsum[t >> 6] = ss;
  __syncthreads();
  const float qnorm = fmaxf(sqrtf(wsum[0] + wsum[1] + wsum[2] + wsum[3]), 1e-8f);

  float best = -3.0e38f;
  int bidx = 0x7fffffff;
  for (int j = t; j < MN; j += 256) {
    const float* mr = me + (size_t)j * DN;
    float dot = 0.f, ms = 0.f;
    for (int k = 0; k < DN; ++k) {
      float a = qr[k], b = mr[k];
      dot += a * b;
      ms += b * b;
    }
    const float sim = dot / (qnorm * fmaxf(sqrtf(ms), 1e-8f));
    if (sim > best) { best = sim; bidx = j; }  // strict > keeps first index
  }
  sred[t] = best;
  sidx[t] = bidx;
  __syncthreads();
  for (int s = 128; s > 0; s >>= 1) {
    if (t < s) {
      const float ov = sred[t + s];
      const int oi = sidx[t + s];
      if (ov > sred[t] || (ov == sred[t] && oi < sidx[t])) {
        sred[t] = ov;
        sidx[t] = oi;
      }
    }
    __syncthreads();
  }
  const float mx = sred[0];
  const int mi = sidx[0];
  if (t < CN)
    out[(size_t)q * CN + t] =
        (mx > 0.7f) ? labels[(size_t)mi * CN + t] : (1.0f / 128.0f);
}

extern "C" void kernel_launch(void* const* d_in, const int* in_sizes, int n_in,
                              void* d_out, int out_size, void* d_ws,
                              size_t ws_size, hipStream_t stream) {
  const float* qe = (const float*)d_in[0];  // [4096,384] f32
  const float* me = (const float*)d_in[1];  // [65536,384] f32
  const float* lb = (const float*)d_in[2];  // [65536,128] f32
  float* out = (float*)d_out;               // [4096,128] f32

  char* ws = (char*)d_ws;
  const size_t OFF_QN = 0;
  const size_t OFF_MN = OFF_QN + (size_t)QN * DN;        // 1,572,864
  const size_t OFF_PMAX = OFF_MN + (size_t)MN * DN;      // +25,165,824
  unsigned char* qn8 = (unsigned char*)(ws + OFF_QN);
  unsigned char* mn8 = (unsigned char*)(ws + OFF_MN);    // fragment-major
  float* pmax = (float*)(ws + OFF_PMAX);                 // [4096][64] = 1 MB

  nrm_kernel<<<(QN + MN) / 4, 256, 0, stream>>>(qe, me, qn8, mn8);
  gemm_max_kernel<<<dim3(QN / 128, NCHUNK), 256, 0, stream>>>(qn8, mn8, pmax);
  decide_kernel<<<QN, 256, 0, stream>>>(pmax, qe, me, lb, out);
}